// Round 3
// baseline (61426.031 us; speedup 1.0000x reference)
//
#include <hip/hip_runtime.h>
#include <hip/hip_cooperative_groups.h>

namespace cg = cooperative_groups;

typedef __attribute__((ext_vector_type(8))) short short8;
typedef __attribute__((ext_vector_type(4))) float floatx4;

#define SEQ 512
#define BS  64
#define HID 1024
#define G4  4096
#define NBLK 128
#define UPB 8    // hidden units per block (32 gate cols)

__device__ __forceinline__ unsigned short f2b(float f) {
  union { float f; unsigned u; } v; v.f = f;
  return (unsigned short)((v.u + 0x7FFFu + ((v.u >> 16) & 1u)) >> 16);
}
__device__ __forceinline__ float b2f(unsigned short s) {
  union { unsigned u; float f; } v; v.u = ((unsigned)s) << 16;
  return v.f;
}

__device__ __forceinline__ void gload_lds16(const void* g, void* l) {
  __builtin_amdgcn_global_load_lds(
      (const __attribute__((address_space(1))) unsigned int*)g,
      (__attribute__((address_space(3))) unsigned int*)l,
      16, 0, 0);
}

// ---- weight transpose+convert: W[1024][4096] f32 -> WT[4096][1024] bf16
__global__ void wtrans(const float* __restrict__ W, short* __restrict__ WT) {
  __shared__ float tile[32][33];
  const int tx = threadIdx.x, ty = threadIdx.y;
  const int n0 = blockIdx.x << 5, k0 = blockIdx.y << 5;
#pragma unroll
  for (int i = 0; i < 32; i += 8)
    tile[ty + i][tx] = W[(size_t)(k0 + ty + i) * G4 + n0 + tx];
  __syncthreads();
#pragma unroll
  for (int i = 0; i < 32; i += 8)
    WT[(size_t)(n0 + ty + i) * 1024 + k0 + tx] = (short)f2b(tile[tx][ty + i]);
}

// ---- projection GEMM: out[M][4096] = A[M][1024](f32) @ WT^T + bias
__global__ __launch_bounds__(256)
void gemm_xw(const float* __restrict__ A, const short* __restrict__ BT,
             const float* __restrict__ bias, void* __restrict__ xw, int xw_f32) {
  __shared__ short Al[128 * 40];
  __shared__ short Bl[128 * 40];
  const int tid = threadIdx.x;
  const int wave = tid >> 6, lane = tid & 63;
  const int lr = lane & 15, lh = lane >> 4;
  const int wm = wave >> 1, wn = wave & 1;
  const int m0 = blockIdx.y << 7;
  const int n0 = blockIdx.x << 7;
  const int arow = tid >> 1, akc = tid & 1;

  const float* aptr = A + (size_t)(m0 + arow) * 1024 + akc * 16;
  const short* bptr = BT + (size_t)(n0 + arow) * 1024 + akc * 16;

  floatx4 acc[4][4] = {};
  floatx4 fa[4];
  short8 pb0, pb1;
#pragma unroll
  for (int j = 0; j < 4; ++j) fa[j] = *(const floatx4*)(aptr + 4 * j);
  pb0 = *(const short8*)(bptr);
  pb1 = *(const short8*)(bptr + 8);

  for (int it = 0; it < 32; ++it) {
    __syncthreads();
    unsigned short us[16];
#pragma unroll
    for (int j = 0; j < 4; ++j)
#pragma unroll
      for (int e = 0; e < 4; ++e) us[4 * j + e] = f2b(fa[j][e]);
    short8 s0, s1;
#pragma unroll
    for (int e = 0; e < 8; ++e) { s0[e] = (short)us[e]; s1[e] = (short)us[8 + e]; }
    *(short8*)&Al[arow * 40 + akc * 16 + 0] = s0;
    *(short8*)&Al[arow * 40 + akc * 16 + 8] = s1;
    *(short8*)&Bl[arow * 40 + akc * 16 + 0] = pb0;
    *(short8*)&Bl[arow * 40 + akc * 16 + 8] = pb1;
    __syncthreads();
    if (it < 31) {
      const int k0 = (it + 1) << 5;
#pragma unroll
      for (int j = 0; j < 4; ++j) fa[j] = *(const floatx4*)(aptr + k0 + 4 * j);
      pb0 = *(const short8*)(bptr + k0);
      pb1 = *(const short8*)(bptr + k0 + 8);
    }
    short8 af[4], bf[4];
#pragma unroll
    for (int mt = 0; mt < 4; ++mt) af[mt] = *(const short8*)&Al[(wm * 64 + mt * 16 + lr) * 40 + lh * 8];
#pragma unroll
    for (int nt = 0; nt < 4; ++nt) bf[nt] = *(const short8*)&Bl[(wn * 64 + nt * 16 + lr) * 40 + lh * 8];
#pragma unroll
    for (int mt = 0; mt < 4; ++mt)
#pragma unroll
      for (int nt = 0; nt < 4; ++nt)
        acc[mt][nt] = __builtin_amdgcn_mfma_f32_16x16x32_bf16(af[mt], bf[nt], acc[mt][nt], 0, 0, 0);
  }
#pragma unroll
  for (int nt = 0; nt < 4; ++nt) {
    const int gcol = n0 + wn * 64 + nt * 16 + lr;
    const float bv = bias[gcol];
#pragma unroll
    for (int mt = 0; mt < 4; ++mt)
#pragma unroll
      for (int r = 0; r < 4; ++r) {
        const int grow = m0 + wm * 64 + mt * 16 + lh * 4 + r;
        const float v = acc[mt][nt][r] + bv;
        if (xw_f32) ((float*)xw)[(size_t)grow * G4 + gcol] = v;
        else        ((unsigned short*)xw)[(size_t)grow * G4 + gcol] = f2b(v);
      }
  }
}

struct Scan3Args {
  const void* xw;          // input projection for this chunk (f32 or bf16)
  const short* wt_hi;      // WT of W_hi [4096][1024] bf16
  unsigned short* hbuf;    // [2][64*1024] bf16 ping-pong
  float* cbuf;             // [64*1024] f32 persistent cell state
  float* hs;               // hs output f32 [512][64][1024]
  float* h_final;
  float* c_final;
  int t0, t1, wr_final;
};

// 128 blocks x 1024 threads (16 waves). Block owns units [8b,8b+8) => 32 gate
// cols. Wave = (wm 0..3, wn 0..1, kh 0..1): M-tile, N-half, K-half.
// W_hi fragments register-resident: breg[16] = 64 VGPR/thread (fits the hard
// 128-VGPR cap of a 1024-thread block; r2's breg[32]=128 spilled to scratch).
template<int XW_F32>
__global__ __launch_bounds__(1024)
void lstm_scan3(Scan3Args p) {
  __shared__ char smem[131072];          // h tile [64][1024] bf16, XOR-swizzled
  float* gsm = (float*)smem;             // overlay after K-loop: [2][64][33] f32
  const int tid = threadIdx.x;
  const int wave = tid >> 6, lane = tid & 63;
  const int lr = lane & 15, lh = lane >> 4;
  const int wm = wave >> 2;              // M tile 0..3 (16 batch rows)
  const int wn = (wave >> 1) & 1;        // N half 0..1 (16 cols)
  const int kh = wave & 1;               // K half 0..1 (512 k each)
  const int blk = blockIdx.x;
  const int nloc = (wn << 4) + lr;                             // 0..31
  const int gcol = ((nloc >> 3) << 10) + blk * UPB + (nloc & 7);
  cg::grid_group grid = cg::this_grid();

  // ---- preload B fragments (W_hi, this wave's K-half): 16 x short8 = 64 VGPR
  short8 breg[16];
  {
    const short* wp = p.wt_hi + (size_t)gcol * HID + (kh << 9) + (lh << 3);
#pragma unroll
    for (int kk = 0; kk < 16; ++kk) breg[kk] = *(const short8*)(wp + (kk << 5));
  }

  // ---- persistent cell state: threads 0..511 own one (batch,unit) each
  const int ub = tid >> 3, uu = tid & 7;
  const int ci = (ub << 10) + blk * UPB + uu;
  float creg = (tid < 512) ? p.cbuf[ci] : 0.f;

  const int arow = (wm << 4) + lr;       // A-frag row for this lane
  const int asw = lr & 7;                // read-side XOR swizzle

  for (int t = p.t0; t < p.t1; ++t) {
    const unsigned short* hb = p.hbuf + (size_t)(t & 1) * (BS * HID);
    unsigned short* hw = p.hbuf + (size_t)((t + 1) & 1) * (BS * HID);

    // ---- stage h_t -> LDS: 8 gload_lds/wave, linear dest, inv-swz source
#pragma unroll
    for (int j = 0; j < 8; ++j) {
      const int i = (wave << 3) + j;     // 0..127 (1KB LDS spans)
      const int row = i >> 1, half = i & 1;
      const int chunk = ((half << 6) + lane) ^ (row & 7);
      gload_lds16(hb + row * HID + (chunk << 3), smem + (i << 10));
    }
    asm volatile("s_waitcnt vmcnt(0)" ::: "memory");
    __builtin_amdgcn_s_barrier();

    // ---- xw loads (kh==0 waves only): hidden under the K loop
    float xv[4] = {0.f, 0.f, 0.f, 0.f};
    if (kh == 0) {
#pragma unroll
      for (int r = 0; r < 4; ++r) {
        const size_t rowi = (size_t)(t - p.t0) * BS + (wm << 4) + (lh << 2) + r;
        if (XW_F32) xv[r] = ((const float*)p.xw)[rowi * G4 + gcol];
        else        xv[r] = b2f(((const unsigned short*)p.xw)[rowi * G4 + gcol]);
      }
    }

    // ---- K loop: 16 x (ds_read_b128 + MFMA), B from registers
    floatx4 acc = {0.f, 0.f, 0.f, 0.f};
#pragma unroll
    for (int kk = 0; kk < 16; ++kk) {
      const int kc = (kh << 6) + (kk << 2) + lh;
      const short8 afr = *(const short8*)(smem + (arow << 11) + ((kc ^ asw) << 4));
      acc = __builtin_amdgcn_mfma_f32_16x16x32_bf16(afr, breg[kk], acc, 0, 0, 0);
    }
    __syncthreads();

    // ---- gate partial sums to LDS overlay (kh 0/1 in separate slots)
#pragma unroll
    for (int r = 0; r < 4; ++r) {
      const int b = (wm << 4) + (lh << 2) + r;
      gsm[((kh << 6) + b) * 33 + nloc] = acc[r] + xv[r];
    }
    __syncthreads();

    // ---- elementwise update: threads 0..511, one (batch,unit) each
    if (tid < 512) {
      const float ig = gsm[ub * 33 + uu]      + gsm[(64 + ub) * 33 + uu];
      const float fg = gsm[ub * 33 + 8 + uu]  + gsm[(64 + ub) * 33 + 8 + uu];
      const float gg = gsm[ub * 33 + 16 + uu] + gsm[(64 + ub) * 33 + 16 + uu];
      const float og = gsm[ub * 33 + 24 + uu] + gsm[(64 + ub) * 33 + 24 + uu];
      const float iv = 1.f / (1.f + __expf(-ig));
      const float fv = 1.f / (1.f + __expf(-fg));
      const float gv = tanhf(gg);
      const float ov = 1.f / (1.f + __expf(-og));
      const float cn = fv * creg + iv * gv;
      creg = cn;
      const float hv = ov * tanhf(cn);
      hw[ci] = f2b(hv);
      p.hs[((size_t)t * BS + ub) * HID + blk * UPB + uu] = hv;
      if (p.wr_final && t == SEQ - 1) { p.h_final[ci] = hv; p.c_final[ci] = cn; }
    }
    __threadfence();
    grid.sync();
  }
  if (tid < 512) p.cbuf[ci] = creg;
}

extern "C" void kernel_launch(void* const* d_in, const int* in_sizes, int n_in,
                              void* d_out, int out_size, void* d_ws, size_t ws_size,
                              hipStream_t stream) {
  const float* x    = (const float*)d_in[0];
  const float* Wii0 = (const float*)d_in[1];
  const float* Wii  = (const float*)d_in[2];
  const float* Whi  = (const float*)d_in[3];
  const float* bias = (const float*)d_in[4];
  float* out  = (float*)d_out;
  float* hs   = out;
  float* hfin = out + (size_t)SEQ * BS * HID;
  float* cfin = hfin + BS * HID;

  char* ws = (char*)d_ws;
  short* WT0 = (short*)ws;
  short* WT1 = WT0 + (size_t)G4 * 1024;
  short* WTh = WT1 + (size_t)G4 * 1024;
  unsigned short* hbuf = (unsigned short*)(WTh + (size_t)G4 * 1024);
  float* cbuf = (float*)(hbuf + 2 * BS * HID);
  char* tail = (char*)(cbuf + BS * HID);
  const size_t head = (size_t)(tail - ws);
  const size_t avail = (ws_size > head) ? ws_size - head : 0;
  const size_t perT_f32 = (size_t)BS * G4 * 4;   // 1 MiB per timestep
  const size_t perT_b16 = (size_t)BS * G4 * 2;

  int chunk, xwF32;
  if      (avail >= SEQ * perT_f32) { chunk = SEQ; xwF32 = 1; }
  else if (avail >= 128 * perT_f32) { chunk = 128; xwF32 = 1; }
  else if (avail >= 32  * perT_f32) { chunk = 32;  xwF32 = 1; }
  else if (avail >= 32  * perT_b16) { chunk = 32;  xwF32 = 0; }
  else                              { chunk = 8;   xwF32 = 0; }

  wtrans<<<dim3(128, 32), dim3(32, 8), 0, stream>>>(Wii0, WT0);
  wtrans<<<dim3(128, 32), dim3(32, 8), 0, stream>>>(Wii, WT1);
  wtrans<<<dim3(128, 32), dim3(32, 8), 0, stream>>>(Whi, WTh);

  const void* scan_fn = xwF32 ? reinterpret_cast<const void*>(&lstm_scan3<1>)
                              : reinterpret_cast<const void*>(&lstm_scan3<0>);

  for (int layer = 0; layer < 2; ++layer) {
    hipMemsetAsync(hbuf, 0, 2 * BS * HID * sizeof(unsigned short), stream);
    hipMemsetAsync(cbuf, 0, BS * HID * sizeof(float), stream);

    for (int t0 = 0; t0 < SEQ; t0 += chunk) {
      const float* Ain = (layer ? hs : x) + (size_t)t0 * BS * 1024;
      gemm_xw<<<dim3(32, chunk * BS / 128), dim3(256), 0, stream>>>(
          Ain, layer ? WT1 : WT0, bias, (void*)tail, xwF32);

      Scan3Args sa;
      sa.xw = (const void*)tail;
      sa.wt_hi = WTh;
      sa.hbuf = hbuf;
      sa.cbuf = cbuf;
      sa.hs = hs;
      sa.h_final = layer ? hfin : nullptr;
      sa.c_final = layer ? cfin : nullptr;
      sa.t0 = t0;
      sa.t1 = t0 + chunk;
      sa.wr_final = layer;
      void* args[] = { &sa };
      hipLaunchCooperativeKernel(scan_fn, dim3(NBLK), dim3(1024), args, 0u, stream);
    }
  }
}

// Round 4
// 8260.627 us; speedup vs baseline: 7.4360x; 7.4360x over previous
//
#include <hip/hip_runtime.h>

typedef __attribute__((ext_vector_type(8))) short short8;
typedef __attribute__((ext_vector_type(4))) float floatx4;

#define SEQ 512
#define BS  64
#define HID 1024
#define G4  4096
#define NBLK 128
#define UPB 8    // hidden units per block (32 gate cols)

__device__ __forceinline__ unsigned short f2b(float f) {
  union { float f; unsigned u; } v; v.f = f;
  return (unsigned short)((v.u + 0x7FFFu + ((v.u >> 16) & 1u)) >> 16);
}
__device__ __forceinline__ float b2f(unsigned short s) {
  union { unsigned u; float f; } v; v.u = ((unsigned)s) << 16;
  return v.f;
}

// device-coherent (cross-XCD) async global->LDS: aux=17 = SC0|SC1
__device__ __forceinline__ void gload_lds16_cc(const void* g, void* l) {
  __builtin_amdgcn_global_load_lds(
      (const __attribute__((address_space(1))) unsigned int*)g,
      (__attribute__((address_space(3))) unsigned int*)l,
      16, 0, 17);
}

// ---- weight transpose+convert: W[1024][4096] f32 -> WT[4096][1024] bf16
__global__ void wtrans(const float* __restrict__ W, short* __restrict__ WT) {
  __shared__ float tile[32][33];
  const int tx = threadIdx.x, ty = threadIdx.y;
  const int n0 = blockIdx.x << 5, k0 = blockIdx.y << 5;
#pragma unroll
  for (int i = 0; i < 32; i += 8)
    tile[ty + i][tx] = W[(size_t)(k0 + ty + i) * G4 + n0 + tx];
  __syncthreads();
#pragma unroll
  for (int i = 0; i < 32; i += 8)
    WT[(size_t)(n0 + ty + i) * 1024 + k0 + tx] = (short)f2b(tile[tx][ty + i]);
}

// ---- projection GEMM: out[M][4096] = A[M][1024](f32) @ WT^T + bias
__global__ __launch_bounds__(256)
void gemm_xw(const float* __restrict__ A, const short* __restrict__ BT,
             const float* __restrict__ bias, void* __restrict__ xw, int xw_f32) {
  __shared__ short Al[128 * 40];
  __shared__ short Bl[128 * 40];
  const int tid = threadIdx.x;
  const int wave = tid >> 6, lane = tid & 63;
  const int lr = lane & 15, lh = lane >> 4;
  const int wm = wave >> 1, wn = wave & 1;
  const int m0 = blockIdx.y << 7;
  const int n0 = blockIdx.x << 7;
  const int arow = tid >> 1, akc = tid & 1;

  const float* aptr = A + (size_t)(m0 + arow) * 1024 + akc * 16;
  const short* bptr = BT + (size_t)(n0 + arow) * 1024 + akc * 16;

  floatx4 acc[4][4] = {};
  floatx4 fa[4];
  short8 pb0, pb1;
#pragma unroll
  for (int j = 0; j < 4; ++j) fa[j] = *(const floatx4*)(aptr + 4 * j);
  pb0 = *(const short8*)(bptr);
  pb1 = *(const short8*)(bptr + 8);

  for (int it = 0; it < 32; ++it) {
    __syncthreads();
    unsigned short us[16];
#pragma unroll
    for (int j = 0; j < 4; ++j)
#pragma unroll
      for (int e = 0; e < 4; ++e) us[4 * j + e] = f2b(fa[j][e]);
    short8 s0, s1;
#pragma unroll
    for (int e = 0; e < 8; ++e) { s0[e] = (short)us[e]; s1[e] = (short)us[8 + e]; }
    *(short8*)&Al[arow * 40 + akc * 16 + 0] = s0;
    *(short8*)&Al[arow * 40 + akc * 16 + 8] = s1;
    *(short8*)&Bl[arow * 40 + akc * 16 + 0] = pb0;
    *(short8*)&Bl[arow * 40 + akc * 16 + 8] = pb1;
    __syncthreads();
    if (it < 31) {
      const int k0 = (it + 1) << 5;
#pragma unroll
      for (int j = 0; j < 4; ++j) fa[j] = *(const floatx4*)(aptr + k0 + 4 * j);
      pb0 = *(const short8*)(bptr + k0);
      pb1 = *(const short8*)(bptr + k0 + 8);
    }
    short8 af[4], bf[4];
#pragma unroll
    for (int mt = 0; mt < 4; ++mt) af[mt] = *(const short8*)&Al[(wm * 64 + mt * 16 + lr) * 40 + lh * 8];
#pragma unroll
    for (int nt = 0; nt < 4; ++nt) bf[nt] = *(const short8*)&Bl[(wn * 64 + nt * 16 + lr) * 40 + lh * 8];
#pragma unroll
    for (int mt = 0; mt < 4; ++mt)
#pragma unroll
      for (int nt = 0; nt < 4; ++nt)
        acc[mt][nt] = __builtin_amdgcn_mfma_f32_16x16x32_bf16(af[mt], bf[nt], acc[mt][nt], 0, 0, 0);
  }
#pragma unroll
  for (int nt = 0; nt < 4; ++nt) {
    const int gcol = n0 + wn * 64 + nt * 16 + lr;
    const float bv = bias[gcol];
#pragma unroll
    for (int mt = 0; mt < 4; ++mt)
#pragma unroll
      for (int r = 0; r < 4; ++r) {
        const int grow = m0 + wm * 64 + mt * 16 + lh * 4 + r;
        const float v = acc[mt][nt][r] + bv;
        if (xw_f32) ((float*)xw)[(size_t)grow * G4 + gcol] = v;
        else        ((unsigned short*)xw)[(size_t)grow * G4 + gcol] = f2b(v);
      }
  }
}

struct Scan4Args {
  const void* xw;          // input projection for this chunk (f32 or bf16)
  const short* wt_hi;      // WT of W_hi [4096][1024] bf16
  unsigned short* hbuf;    // [2][64*1024] bf16 ping-pong (device-coherent traffic)
  float* cbuf;             // [64*1024] f32 persistent cell state
  unsigned int* flags;     // [NBLK] u32, padded to 64B each
  float* hs;               // hs output f32 [512][64][1024]
  float* h_final;
  float* c_final;
  int t0, t1, wr_final;
};

// 128 blocks x 1024 threads (16 waves). Block owns units [8b,8b+8) => 32 gate
// cols. Wave = (wm 0..3, wn 0..1, kh 0..1). W_hi register-resident (breg[16]).
// Cross-block h exchange: sc0sc1 write-through stores + sc1 staging reads +
// per-block flag barrier. NO grid.sync, NO threadfence => no L2 flush/inv.
template<int XW_F32>
__global__ __launch_bounds__(1024)
void lstm_scan4(Scan4Args p) {
  __shared__ char smem[131072];          // h tile [64][1024] bf16, XOR-swizzled
  float* gsm = (float*)smem;             // overlay after K-loop: [2][64][33] f32
  unsigned short* hpk = (unsigned short*)(smem + 20480);  // [64][8] bf16 pack
  const int tid = threadIdx.x;
  const int wave = tid >> 6, lane = tid & 63;
  const int lr = lane & 15, lh = lane >> 4;
  const int wm = wave >> 2;              // M tile 0..3 (16 batch rows)
  const int wn = (wave >> 1) & 1;        // N half 0..1 (16 cols)
  const int kh = wave & 1;               // K half 0..1 (512 k each)
  const int blk = blockIdx.x;
  const int nloc = (wn << 4) + lr;                             // 0..31
  const int gcol = ((nloc >> 3) << 10) + blk * UPB + (nloc & 7);

  // ---- preload B fragments (W_hi, this wave's K-half): 16 x short8 = 64 regs
  short8 breg[16];
  {
    const short* wp = p.wt_hi + (size_t)gcol * HID + (kh << 9) + (lh << 3);
#pragma unroll
    for (int kk = 0; kk < 16; ++kk) breg[kk] = *(const short8*)(wp + (kk << 5));
  }

  // ---- persistent cell state: threads 0..511 own one (batch,unit) each
  const int ub = tid >> 3, uu = tid & 7;
  const int ci = (ub << 10) + blk * UPB + uu;
  float creg = (tid < 512) ? p.cbuf[ci] : 0.f;

  const int arow = (wm << 4) + lr;       // A-frag row for this lane
  const int asw = lr & 7;                // read-side XOR swizzle

  // poll addresses (wave 0 only uses them)
  const unsigned long long fa0 = (unsigned long long)(p.flags + (size_t)lane * 16);
  const unsigned long long fa1 = (unsigned long long)(p.flags + (size_t)(64 + lane) * 16);

  for (int t = p.t0; t < p.t1; ++t) {
    // ---- barrier-in: wait until every block has published h for step t
    if (t > 0 && wave == 0) {
      unsigned f0, f1;
      do {
        asm volatile("global_load_dword %0, %2, off sc0 sc1\n\t"
                     "global_load_dword %1, %3, off sc0 sc1\n\t"
                     "s_waitcnt vmcnt(0)"
                     : "=v"(f0), "=v"(f1) : "v"(fa0), "v"(fa1) : "memory");
      } while (!__all(f0 >= (unsigned)t && f1 >= (unsigned)t));
    }
    __syncthreads();   // releases all waves; also closes prev-iter LDS use

    const unsigned short* hb = p.hbuf + (size_t)(t & 1) * (BS * HID);
    unsigned short* hw = p.hbuf + (size_t)((t + 1) & 1) * (BS * HID);

    // ---- stage h_t -> LDS: 8 coherent gload_lds/wave, linear dest, inv-swz src
#pragma unroll
    for (int j = 0; j < 8; ++j) {
      const int i = (wave << 3) + j;     // 0..127 (1KB LDS spans)
      const int row = i >> 1, half = i & 1;
      const int chunk = ((half << 6) + lane) ^ (row & 7);
      gload_lds16_cc(hb + row * HID + (chunk << 3), smem + (i << 10));
    }
    asm volatile("s_waitcnt vmcnt(0)" ::: "memory");
    __builtin_amdgcn_s_barrier();

    // ---- xw loads (kh==0 waves only): overlapped with K loop
    float xv[4] = {0.f, 0.f, 0.f, 0.f};
    if (kh == 0) {
#pragma unroll
      for (int r = 0; r < 4; ++r) {
        const size_t rowi = (size_t)(t - p.t0) * BS + (wm << 4) + (lh << 2) + r;
        if (XW_F32) xv[r] = ((const float*)p.xw)[rowi * G4 + gcol];
        else        xv[r] = b2f(((const unsigned short*)p.xw)[rowi * G4 + gcol]);
      }
    }

    // ---- K loop: 16 x (ds_read_b128 + MFMA), B from registers
    floatx4 acc = {0.f, 0.f, 0.f, 0.f};
#pragma unroll
    for (int kk = 0; kk < 16; ++kk) {
      const int kc = (kh << 6) + (kk << 2) + lh;
      const short8 afr = *(const short8*)(smem + (arow << 11) + ((kc ^ asw) << 4));
      acc = __builtin_amdgcn_mfma_f32_16x16x32_bf16(afr, breg[kk], acc, 0, 0, 0);
    }
    __syncthreads();

    // ---- gate partial sums to LDS overlay (kh 0/1 in separate slots)
#pragma unroll
    for (int r = 0; r < 4; ++r) {
      const int b = (wm << 4) + (lh << 2) + r;
      gsm[((kh << 6) + b) * 33 + nloc] = acc[r] + xv[r];
    }
    __syncthreads();

    // ---- elementwise update: threads 0..511, one (batch,unit) each
    if (tid < 512) {
      const float ig = gsm[ub * 33 + uu]      + gsm[(64 + ub) * 33 + uu];
      const float fg = gsm[ub * 33 + 8 + uu]  + gsm[(64 + ub) * 33 + 8 + uu];
      const float gg = gsm[ub * 33 + 16 + uu] + gsm[(64 + ub) * 33 + 16 + uu];
      const float og = gsm[ub * 33 + 24 + uu] + gsm[(64 + ub) * 33 + 24 + uu];
      const float iv = 1.f / (1.f + __expf(-ig));
      const float fv = 1.f / (1.f + __expf(-fg));
      const float gv = tanhf(gg);
      const float ov = 1.f / (1.f + __expf(-og));
      const float cn = fv * creg + iv * gv;
      creg = cn;
      const float hv = ov * tanhf(cn);
      hpk[(ub << 3) + uu] = f2b(hv);
      p.hs[((size_t)t * BS + ub) * HID + blk * UPB + uu] = hv;
      if (p.wr_final && t == SEQ - 1) { p.h_final[ci] = hv; p.c_final[ci] = cn; }
    }
    __syncthreads();

    // ---- publish h slice: 256 coherent u32 stores, then flag
    if (tid < 256) {
      const unsigned val = ((const unsigned*)hpk)[tid];
      const int row = tid >> 2, word = tid & 3;
      const unsigned long long dst =
          (unsigned long long)(hw + (size_t)row * HID + blk * UPB + word * 2);
      asm volatile("global_store_dword %0, %1, off sc0 sc1"
                   :: "v"(dst), "v"(val) : "memory");
    }
    asm volatile("s_waitcnt vmcnt(0)" ::: "memory");
    __syncthreads();   // all waves' coherent stores retired before flag
    if (tid == 0) {
      const unsigned long long fdst = (unsigned long long)(p.flags + (size_t)blk * 16);
      const unsigned fval = (unsigned)(t + 1);
      asm volatile("global_store_dword %0, %1, off sc0 sc1"
                   :: "v"(fdst), "v"(fval) : "memory");
    }
  }
  if (tid < 512) p.cbuf[ci] = creg;
}

extern "C" void kernel_launch(void* const* d_in, const int* in_sizes, int n_in,
                              void* d_out, int out_size, void* d_ws, size_t ws_size,
                              hipStream_t stream) {
  const float* x    = (const float*)d_in[0];
  const float* Wii0 = (const float*)d_in[1];
  const float* Wii  = (const float*)d_in[2];
  const float* Whi  = (const float*)d_in[3];
  const float* bias = (const float*)d_in[4];
  float* out  = (float*)d_out;
  float* hs   = out;
  float* hfin = out + (size_t)SEQ * BS * HID;
  float* cfin = hfin + BS * HID;

  char* ws = (char*)d_ws;
  short* WT0 = (short*)ws;
  short* WT1 = WT0 + (size_t)G4 * 1024;
  short* WTh = WT1 + (size_t)G4 * 1024;
  unsigned short* hbuf = (unsigned short*)(WTh + (size_t)G4 * 1024);
  float* cbuf = (float*)(hbuf + 2 * BS * HID);
  unsigned int* flags = (unsigned int*)(cbuf + BS * HID);   // 128 * 64B
  char* tail = (char*)(flags + NBLK * 16);
  const size_t head = (size_t)(tail - ws);
  const size_t avail = (ws_size > head) ? ws_size - head : 0;
  const size_t perT_f32 = (size_t)BS * G4 * 4;   // 1 MiB per timestep
  const size_t perT_b16 = (size_t)BS * G4 * 2;

  int chunk, xwF32;
  if      (avail >= SEQ * perT_f32) { chunk = SEQ; xwF32 = 1; }
  else if (avail >= 128 * perT_f32) { chunk = 128; xwF32 = 1; }
  else if (avail >= 32  * perT_f32) { chunk = 32;  xwF32 = 1; }
  else if (avail >= 32  * perT_b16) { chunk = 32;  xwF32 = 0; }
  else                              { chunk = 8;   xwF32 = 0; }

  wtrans<<<dim3(128, 32), dim3(32, 8), 0, stream>>>(Wii0, WT0);
  wtrans<<<dim3(128, 32), dim3(32, 8), 0, stream>>>(Wii, WT1);
  wtrans<<<dim3(128, 32), dim3(32, 8), 0, stream>>>(Whi, WTh);

  const void* scan_fn = xwF32 ? reinterpret_cast<const void*>(&lstm_scan4<1>)
                              : reinterpret_cast<const void*>(&lstm_scan4<0>);

  for (int layer = 0; layer < 2; ++layer) {
    hipMemsetAsync(hbuf, 0, 2 * BS * HID * sizeof(unsigned short), stream);
    hipMemsetAsync(cbuf, 0, BS * HID * sizeof(float), stream);
    hipMemsetAsync(flags, 0, NBLK * 16 * sizeof(unsigned int), stream);

    for (int t0 = 0; t0 < SEQ; t0 += chunk) {
      const float* Ain = (layer ? hs : x) + (size_t)t0 * BS * 1024;
      gemm_xw<<<dim3(32, chunk * BS / 128), dim3(256), 0, stream>>>(
          Ain, layer ? WT1 : WT0, bias, (void*)tail, xwF32);

      Scan4Args sa;
      sa.xw = (const void*)tail;
      sa.wt_hi = WTh;
      sa.hbuf = hbuf;
      sa.cbuf = cbuf;
      sa.flags = flags;
      sa.hs = hs;
      sa.h_final = layer ? hfin : nullptr;
      sa.c_final = layer ? cfin : nullptr;
      sa.t0 = t0;
      sa.t1 = t0 + chunk;
      sa.wr_final = layer;
      void* args[] = { &sa };
      hipLaunchCooperativeKernel(scan_fn, dim3(NBLK), dim3(1024), args, 0u, stream);
    }
  }
}

// Round 5
// 5222.448 us; speedup vs baseline: 11.7619x; 1.5818x over previous
//
#include <hip/hip_runtime.h>

typedef __attribute__((ext_vector_type(8))) short short8;
typedef __attribute__((ext_vector_type(4))) float floatx4;

#define SEQ 512
#define BS  64
#define HID 1024
#define G4  4096
#define NBLK 128
#define NGRP 4    // batch groups
#define BPG  32   // blocks per group
#define GBS  16   // batch rows per group
#define UPB  32   // hidden units per block

__device__ __forceinline__ unsigned short f2b(float f) {
  union { float f; unsigned u; } v; v.f = f;
  return (unsigned short)((v.u + 0x7FFFu + ((v.u >> 16) & 1u)) >> 16);
}
__device__ __forceinline__ float b2f(unsigned short s) {
  union { unsigned u; float f; } v; v.u = ((unsigned)s) << 16;
  return v.f;
}

// device-coherent (cross-XCD) async global->LDS: aux=17 = SC0|SC1
__device__ __forceinline__ void gload_lds16_cc(const void* g, void* l) {
  __builtin_amdgcn_global_load_lds(
      (const __attribute__((address_space(1))) unsigned int*)g,
      (__attribute__((address_space(3))) unsigned int*)l,
      16, 0, 17);
}

// ---- weight transpose+convert: W[1024][4096] f32 -> WT[4096][1024] bf16
__global__ void wtrans(const float* __restrict__ W, short* __restrict__ WT) {
  __shared__ float tile[32][33];
  const int tx = threadIdx.x, ty = threadIdx.y;
  const int n0 = blockIdx.x << 5, k0 = blockIdx.y << 5;
#pragma unroll
  for (int i = 0; i < 32; i += 8)
    tile[ty + i][tx] = W[(size_t)(k0 + ty + i) * G4 + n0 + tx];
  __syncthreads();
#pragma unroll
  for (int i = 0; i < 32; i += 8)
    WT[(size_t)(n0 + ty + i) * 1024 + k0 + tx] = (short)f2b(tile[tx][ty + i]);
}

// ---- projection GEMM: out[M][4096] = A[M][1024](f32) @ WT^T + bias
__global__ __launch_bounds__(256)
void gemm_xw(const float* __restrict__ A, const short* __restrict__ BT,
             const float* __restrict__ bias, void* __restrict__ xw, int xw_f32) {
  __shared__ short Al[128 * 40];
  __shared__ short Bl[128 * 40];
  const int tid = threadIdx.x;
  const int wave = tid >> 6, lane = tid & 63;
  const int lr = lane & 15, lh = lane >> 4;
  const int wm = wave >> 1, wn = wave & 1;
  const int m0 = blockIdx.y << 7;
  const int n0 = blockIdx.x << 7;
  const int arow = tid >> 1, akc = tid & 1;

  const float* aptr = A + (size_t)(m0 + arow) * 1024 + akc * 16;
  const short* bptr = BT + (size_t)(n0 + arow) * 1024 + akc * 16;

  floatx4 acc[4][4] = {};
  floatx4 fa[4];
  short8 pb0, pb1;
#pragma unroll
  for (int j = 0; j < 4; ++j) fa[j] = *(const floatx4*)(aptr + 4 * j);
  pb0 = *(const short8*)(bptr);
  pb1 = *(const short8*)(bptr + 8);

  for (int it = 0; it < 32; ++it) {
    __syncthreads();
    unsigned short us[16];
#pragma unroll
    for (int j = 0; j < 4; ++j)
#pragma unroll
      for (int e = 0; e < 4; ++e) us[4 * j + e] = f2b(fa[j][e]);
    short8 s0, s1;
#pragma unroll
    for (int e = 0; e < 8; ++e) { s0[e] = (short)us[e]; s1[e] = (short)us[8 + e]; }
    *(short8*)&Al[arow * 40 + akc * 16 + 0] = s0;
    *(short8*)&Al[arow * 40 + akc * 16 + 8] = s1;
    *(short8*)&Bl[arow * 40 + akc * 16 + 0] = pb0;
    *(short8*)&Bl[arow * 40 + akc * 16 + 8] = pb1;
    __syncthreads();
    if (it < 31) {
      const int k0 = (it + 1) << 5;
#pragma unroll
      for (int j = 0; j < 4; ++j) fa[j] = *(const floatx4*)(aptr + k0 + 4 * j);
      pb0 = *(const short8*)(bptr + k0);
      pb1 = *(const short8*)(bptr + k0 + 8);
    }
    short8 af[4], bf[4];
#pragma unroll
    for (int mt = 0; mt < 4; ++mt) af[mt] = *(const short8*)&Al[(wm * 64 + mt * 16 + lr) * 40 + lh * 8];
#pragma unroll
    for (int nt = 0; nt < 4; ++nt) bf[nt] = *(const short8*)&Bl[(wn * 64 + nt * 16 + lr) * 40 + lh * 8];
#pragma unroll
    for (int mt = 0; mt < 4; ++mt)
#pragma unroll
      for (int nt = 0; nt < 4; ++nt)
        acc[mt][nt] = __builtin_amdgcn_mfma_f32_16x16x32_bf16(af[mt], bf[nt], acc[mt][nt], 0, 0, 0);
  }
#pragma unroll
  for (int nt = 0; nt < 4; ++nt) {
    const int gcol = n0 + wn * 64 + nt * 16 + lr;
    const float bv = bias[gcol];
#pragma unroll
    for (int mt = 0; mt < 4; ++mt)
#pragma unroll
      for (int r = 0; r < 4; ++r) {
        const int grow = m0 + wm * 64 + mt * 16 + lh * 4 + r;
        const float v = acc[mt][nt][r] + bv;
        if (xw_f32) ((float*)xw)[(size_t)grow * G4 + gcol] = v;
        else        ((unsigned short*)xw)[(size_t)grow * G4 + gcol] = f2b(v);
      }
  }
}

struct Scan5Args {
  const void* xw;          // input projection for this chunk (f32 or bf16)
  const short* wt_hi;      // WT of W_hi [4096][1024] bf16
  unsigned short* hbuf;    // [2][64*1024] bf16 ping-pong (device-coherent traffic)
  float* cbuf;             // [64*1024] f32 persistent cell state
  unsigned int* flags;     // [NBLK] u32, padded to 64B each
  float* hs;               // hs output f32 [512][64][1024]
  float* h_final;
  float* c_final;
  int t0, t1, wr_final;
};

// 128 blocks x 1024 threads = 4 batch-groups x 32 blocks. Group g owns batch
// rows [16g,16g+16); block in group owns 32 hidden units (128 gate cols).
// Wave = (nt 0..7, kh 0..1): N-tile (16 cols), K-half (512 k). breg[16]=64reg.
// Cross-block h exchange only within a group (32 KB): sc0sc1 write-through
// stores + coherent staging reads + per-group flag barrier. Groups drift free.
template<int XW_F32>
__global__ __launch_bounds__(1024)
void lstm_scan5(Scan5Args p) {
  __shared__ char smem[50688];
  // [0,32768): h tile [16 rows][2048B], XOR-swizzled
  // [32768, 49664): gsm [2kh][4 gate][16 b][33] f32
  // [49664, 50688): hpk [16 b][32 u] bf16
  float* gsm = (float*)(smem + 32768);
  unsigned short* hpk = (unsigned short*)(smem + 49664);
  const int tid = threadIdx.x;
  const int wave = tid >> 6, lane = tid & 63;
  const int lr = lane & 15, lh = lane >> 4;
  const int nt = wave >> 1;              // N tile 0..7
  const int kh = wave & 1;               // K half 0..1
  const int blk = blockIdx.x;
  const int g = blk >> 5;                // batch group 0..3
  const int ub_idx = blk & 31;           // unit-block within hidden dim
  const int gcol = ((nt >> 1) << 10) + ub_idx * UPB + ((nt & 1) << 4) + lr;

  // ---- preload B fragments (W_hi, this wave's K-half): 16 x short8
  short8 breg[16];
  {
    const short* wp = p.wt_hi + (size_t)gcol * HID + (kh << 9) + (lh << 3);
#pragma unroll
    for (int kk = 0; kk < 16; ++kk) breg[kk] = *(const short8*)(wp + (kk << 5));
  }

  // ---- persistent cell state: threads 0..511 own one (batch,unit) each
  const int b_loc = tid >> 5, u_loc = tid & 31;          // for update phase
  const int ci = ((g * GBS + b_loc) << 10) + ub_idx * UPB + u_loc;
  float creg = (tid < 512) ? p.cbuf[ci] : 0.f;

  const int asw = lr & 7;                // read-side XOR swizzle (row = lr)

  // poll address: this group's 32 flags
  const unsigned long long fad =
      (unsigned long long)(p.flags + ((size_t)(g * BPG) + (lane & 31)) * 16);

  for (int t = p.t0; t < p.t1; ++t) {
    // ---- barrier-in: wait until the group has published h for step t
    if (t > 0 && wave == 0) {
      unsigned f0;
      do {
        asm volatile("global_load_dword %0, %1, off sc0 sc1\n\t"
                     "s_waitcnt vmcnt(0)"
                     : "=v"(f0) : "v"(fad) : "memory");
      } while (!__all(f0 >= (unsigned)t));
    }
    __syncthreads();   // releases all waves; also closes prev-iter LDS use

    const unsigned short* hb = p.hbuf + (size_t)(t & 1) * (BS * HID) + (size_t)g * GBS * HID;
    unsigned short* hw = p.hbuf + (size_t)((t + 1) & 1) * (BS * HID) + (size_t)g * GBS * HID;

    // ---- stage group h_t (32KB) -> LDS: 2 coherent gload_lds/wave
#pragma unroll
    for (int j = 0; j < 2; ++j) {
      const int i = (wave << 1) + j;     // 0..31 (1KB LDS spans)
      const int row = i >> 1, half = i & 1;
      const int chunk = ((half << 6) + lane) ^ (row & 7);
      gload_lds16_cc(hb + row * HID + (chunk << 3), smem + (i << 10));
    }
    asm volatile("s_waitcnt vmcnt(0)" ::: "memory");
    __builtin_amdgcn_s_barrier();

    // ---- xw loads (kh==0 waves): overlapped with K loop by the scheduler
    float xv[4] = {0.f, 0.f, 0.f, 0.f};
    if (kh == 0) {
#pragma unroll
      for (int r = 0; r < 4; ++r) {
        const size_t rowi = (size_t)(t - p.t0) * BS + g * GBS + (lh << 2) + r;
        if (XW_F32) xv[r] = ((const float*)p.xw)[rowi * G4 + gcol];
        else        xv[r] = b2f(((const unsigned short*)p.xw)[rowi * G4 + gcol]);
      }
    }

    // ---- K loop: 16 x (ds_read_b128 + MFMA), B from registers
    floatx4 acc = {0.f, 0.f, 0.f, 0.f};
#pragma unroll
    for (int kk = 0; kk < 16; ++kk) {
      const int kc = (kh << 6) + (kk << 2) + lh;
      const short8 afr = *(const short8*)(smem + (lr << 11) + ((kc ^ asw) << 4));
      acc = __builtin_amdgcn_mfma_f32_16x16x32_bf16(afr, breg[kk], acc, 0, 0, 0);
    }

    // ---- gate partial sums to gsm (separate LDS region; no barrier needed)
    {
      const int gate = nt >> 1, ub16 = (nt & 1) << 4;
#pragma unroll
      for (int r = 0; r < 4; ++r) {
        const int b = (lh << 2) + r;
        gsm[((kh << 2) + gate) * 528 + b * 33 + ub16 + lr] = acc[r] + xv[r];
      }
    }
    __syncthreads();

    // ---- elementwise update: threads 0..511, one (batch,unit) each
    if (tid < 512) {
      const int o = b_loc * 33 + u_loc;
      const float ig = gsm[o]            + gsm[4 * 528 + o];
      const float fg = gsm[1 * 528 + o]  + gsm[5 * 528 + o];
      const float gg = gsm[2 * 528 + o]  + gsm[6 * 528 + o];
      const float og = gsm[3 * 528 + o]  + gsm[7 * 528 + o];
      const float iv = 1.f / (1.f + __expf(-ig));
      const float fv = 1.f / (1.f + __expf(-fg));
      const float gv = tanhf(gg);
      const float ov = 1.f / (1.f + __expf(-og));
      const float cn = fv * creg + iv * gv;
      creg = cn;
      const float hv = ov * tanhf(cn);
      hpk[(b_loc << 5) + u_loc] = f2b(hv);
      p.hs[((size_t)t * BS + g * GBS + b_loc) * HID + ub_idx * UPB + u_loc] = hv;
      if (p.wr_final && t == SEQ - 1) { p.h_final[ci] = hv; p.c_final[ci] = cn; }
    }
    __syncthreads();

    // ---- publish h slice: 256 coherent u32 stores, then flag
    if (tid < 256) {
      const unsigned val = ((const unsigned*)hpk)[tid];
      const int row = tid >> 4, word = tid & 15;
      const unsigned long long dst =
          (unsigned long long)(hw + (size_t)row * HID + ub_idx * UPB + word * 2);
      asm volatile("global_store_dword %0, %1, off sc0 sc1"
                   :: "v"(dst), "v"(val) : "memory");
    }
    asm volatile("s_waitcnt vmcnt(0)" ::: "memory");
    __syncthreads();   // all coherent stores retired before flag
    if (tid == 0) {
      const unsigned long long fdst = (unsigned long long)(p.flags + (size_t)blk * 16);
      const unsigned fval = (unsigned)(t + 1);
      asm volatile("global_store_dword %0, %1, off sc0 sc1"
                   :: "v"(fdst), "v"(fval) : "memory");
    }
  }
  if (tid < 512) p.cbuf[ci] = creg;
}

extern "C" void kernel_launch(void* const* d_in, const int* in_sizes, int n_in,
                              void* d_out, int out_size, void* d_ws, size_t ws_size,
                              hipStream_t stream) {
  const float* x    = (const float*)d_in[0];
  const float* Wii0 = (const float*)d_in[1];
  const float* Wii  = (const float*)d_in[2];
  const float* Whi  = (const float*)d_in[3];
  const float* bias = (const float*)d_in[4];
  float* out  = (float*)d_out;
  float* hs   = out;
  float* hfin = out + (size_t)SEQ * BS * HID;
  float* cfin = hfin + BS * HID;

  char* ws = (char*)d_ws;
  short* WT0 = (short*)ws;
  short* WT1 = WT0 + (size_t)G4 * 1024;
  short* WTh = WT1 + (size_t)G4 * 1024;
  unsigned short* hbuf = (unsigned short*)(WTh + (size_t)G4 * 1024);
  float* cbuf = (float*)(hbuf + 2 * BS * HID);
  unsigned int* flags = (unsigned int*)(cbuf + BS * HID);   // 128 * 64B
  char* tail = (char*)(flags + NBLK * 16);
  const size_t head = (size_t)(tail - ws);
  const size_t avail = (ws_size > head) ? ws_size - head : 0;
  const size_t perT_f32 = (size_t)BS * G4 * 4;   // 1 MiB per timestep
  const size_t perT_b16 = (size_t)BS * G4 * 2;

  int chunk, xwF32;
  if      (avail >= SEQ * perT_f32) { chunk = SEQ; xwF32 = 1; }
  else if (avail >= 128 * perT_f32) { chunk = 128; xwF32 = 1; }
  else if (avail >= 32  * perT_f32) { chunk = 32;  xwF32 = 1; }
  else if (avail >= 32  * perT_b16) { chunk = 32;  xwF32 = 0; }
  else                              { chunk = 8;   xwF32 = 0; }

  wtrans<<<dim3(128, 32), dim3(32, 8), 0, stream>>>(Wii0, WT0);
  wtrans<<<dim3(128, 32), dim3(32, 8), 0, stream>>>(Wii, WT1);
  wtrans<<<dim3(128, 32), dim3(32, 8), 0, stream>>>(Whi, WTh);

  const void* scan_fn = xwF32 ? reinterpret_cast<const void*>(&lstm_scan5<1>)
                              : reinterpret_cast<const void*>(&lstm_scan5<0>);

  for (int layer = 0; layer < 2; ++layer) {
    hipMemsetAsync(hbuf, 0, 2 * BS * HID * sizeof(unsigned short), stream);
    hipMemsetAsync(cbuf, 0, BS * HID * sizeof(float), stream);
    hipMemsetAsync(flags, 0, NBLK * 16 * sizeof(unsigned int), stream);

    for (int t0 = 0; t0 < SEQ; t0 += chunk) {
      const float* Ain = (layer ? hs : x) + (size_t)t0 * BS * 1024;
      gemm_xw<<<dim3(32, chunk * BS / 128), dim3(256), 0, stream>>>(
          Ain, layer ? WT1 : WT0, bias, (void*)tail, xwF32);

      Scan5Args sa;
      sa.xw = (const void*)tail;
      sa.wt_hi = WTh;
      sa.hbuf = hbuf;
      sa.cbuf = cbuf;
      sa.flags = flags;
      sa.hs = hs;
      sa.h_final = layer ? hfin : nullptr;
      sa.c_final = layer ? cfin : nullptr;
      sa.t0 = t0;
      sa.t1 = t0 + chunk;
      sa.wr_final = layer;
      void* args[] = { &sa };
      hipLaunchCooperativeKernel(scan_fn, dim3(NBLK), dim3(1024), args, 0u, stream);
    }
  }
}

// Round 6
// 4952.349 us; speedup vs baseline: 12.4034x; 1.0545x over previous
//
#include <hip/hip_runtime.h>

typedef __attribute__((ext_vector_type(8))) short short8;
typedef __attribute__((ext_vector_type(4))) short short4v;
typedef __attribute__((ext_vector_type(4))) float floatx4;

#define SEQ 512
#define BS  64
#define HID 1024
#define G4  4096
#define NBLK 128
#define NGRP 4    // batch groups
#define BPG  32   // blocks per group
#define GBS  16   // batch rows per group
#define UPB  32   // hidden units per block

__device__ __forceinline__ unsigned short f2b(float f) {
  union { float f; unsigned u; } v; v.f = f;
  return (unsigned short)((v.u + 0x7FFFu + ((v.u >> 16) & 1u)) >> 16);
}
__device__ __forceinline__ float b2f(unsigned short s) {
  union { unsigned u; float f; } v; v.u = ((unsigned)s) << 16;
  return v.f;
}

// device-coherent (cross-XCD) async global->LDS: aux=17 = SC0|SC1
__device__ __forceinline__ void gload_lds16_cc(const void* g, void* l) {
  __builtin_amdgcn_global_load_lds(
      (const __attribute__((address_space(1))) unsigned int*)g,
      (__attribute__((address_space(3))) unsigned int*)l,
      16, 0, 17);
}

// ---- weight transpose+convert: W[1024][4096] f32 -> WT[4096][1024] bf16
__global__ void wtrans(const float* __restrict__ W, short* __restrict__ WT) {
  __shared__ float tile[32][33];
  const int tx = threadIdx.x, ty = threadIdx.y;
  const int n0 = blockIdx.x << 5, k0 = blockIdx.y << 5;
#pragma unroll
  for (int i = 0; i < 32; i += 8)
    tile[ty + i][tx] = W[(size_t)(k0 + ty + i) * G4 + n0 + tx];
  __syncthreads();
#pragma unroll
  for (int i = 0; i < 32; i += 8)
    WT[(size_t)(n0 + ty + i) * 1024 + k0 + tx] = (short)f2b(tile[tx][ty + i]);
}

// ---- standalone projection GEMM (prologue only): out[M][4096] = A @ WT^T + b
__global__ __launch_bounds__(256)
void gemm_xw(const float* __restrict__ A, const short* __restrict__ BT,
             const float* __restrict__ bias, void* __restrict__ xw, int xw_f32) {
  __shared__ short Al[128 * 40];
  __shared__ short Bl[128 * 40];
  const int tid = threadIdx.x;
  const int wave = tid >> 6, lane = tid & 63;
  const int lr = lane & 15, lh = lane >> 4;
  const int wm = wave >> 1, wn = wave & 1;
  const int m0 = blockIdx.y << 7;
  const int n0 = blockIdx.x << 7;
  const int arow = tid >> 1, akc = tid & 1;

  const float* aptr = A + (size_t)(m0 + arow) * 1024 + akc * 16;
  const short* bptr = BT + (size_t)(n0 + arow) * 1024 + akc * 16;

  floatx4 acc[4][4] = {};
  floatx4 fa[4];
  short8 pb0, pb1;
#pragma unroll
  for (int j = 0; j < 4; ++j) fa[j] = *(const floatx4*)(aptr + 4 * j);
  pb0 = *(const short8*)(bptr);
  pb1 = *(const short8*)(bptr + 8);

  for (int it = 0; it < 32; ++it) {
    __syncthreads();
    unsigned short us[16];
#pragma unroll
    for (int j = 0; j < 4; ++j)
#pragma unroll
      for (int e = 0; e < 4; ++e) us[4 * j + e] = f2b(fa[j][e]);
    short8 s0, s1;
#pragma unroll
    for (int e = 0; e < 8; ++e) { s0[e] = (short)us[e]; s1[e] = (short)us[8 + e]; }
    *(short8*)&Al[arow * 40 + akc * 16 + 0] = s0;
    *(short8*)&Al[arow * 40 + akc * 16 + 8] = s1;
    *(short8*)&Bl[arow * 40 + akc * 16 + 0] = pb0;
    *(short8*)&Bl[arow * 40 + akc * 16 + 8] = pb1;
    __syncthreads();
    if (it < 31) {
      const int k0 = (it + 1) << 5;
#pragma unroll
      for (int j = 0; j < 4; ++j) fa[j] = *(const floatx4*)(aptr + k0 + 4 * j);
      pb0 = *(const short8*)(bptr + k0);
      pb1 = *(const short8*)(bptr + k0 + 8);
    }
    short8 af[4], bf[4];
#pragma unroll
    for (int mt = 0; mt < 4; ++mt) af[mt] = *(const short8*)&Al[(wm * 64 + mt * 16 + lr) * 40 + lh * 8];
#pragma unroll
    for (int nt = 0; nt < 4; ++nt) bf[nt] = *(const short8*)&Bl[(wn * 64 + nt * 16 + lr) * 40 + lh * 8];
#pragma unroll
    for (int mt = 0; mt < 4; ++mt)
#pragma unroll
      for (int nt = 0; nt < 4; ++nt)
        acc[mt][nt] = __builtin_amdgcn_mfma_f32_16x16x32_bf16(af[mt], bf[nt], acc[mt][nt], 0, 0, 0);
  }
#pragma unroll
  for (int nt = 0; nt < 4; ++nt) {
    const int gcol = n0 + wn * 64 + nt * 16 + lr;
    const float bv = bias[gcol];
#pragma unroll
    for (int mt = 0; mt < 4; ++mt)
#pragma unroll
      for (int r = 0; r < 4; ++r) {
        const int grow = m0 + wm * 64 + mt * 16 + lh * 4 + r;
        const float v = acc[mt][nt][r] + bv;
        if (xw_f32) ((float*)xw)[(size_t)grow * G4 + gcol] = v;
        else        ((unsigned short*)xw)[(size_t)grow * G4 + gcol] = f2b(v);
      }
  }
}

struct FusedArgs {
  // scan (blocks 0..127): recurrence for chunk [t0,t1) reading xw
  const void* xw;
  const short* wt_hi;
  unsigned short* hbuf;    // [2][64*1024] bf16 ping-pong (coherent traffic)
  float* cbuf;             // [64*1024] f32 persistent cell state
  unsigned int* flags;     // [NBLK] u32 padded to 64B
  float* hs;               // [512][64][1024] f32 output
  float* h_final;
  float* c_final;
  int t0, t1, wr_final;
  // gemm (blocks 128..255): xw for the NEXT chunk -> dst
  const float* A;          // [Mrows][1024] f32
  const short* BT;         // WT [4096][1024] bf16
  const float* bias;
  void* dst;
  int Mrows, genable;
};

// ---- scan body: identical geometry to r5 lstm_scan5 + micro-opts
template<int XW_F32>
__device__ __forceinline__ void scan_body(const FusedArgs& p, char* smem) {
  // [0,32768): h tile [16 rows][2048B] XOR-swizzled; [32768,+16896): gsm
  float* gsm = (float*)(smem + 32768);
  const int tid = threadIdx.x;
  const int wave = tid >> 6, lane = tid & 63;
  const int lr = lane & 15, lh = lane >> 4;
  const int nt = wave >> 1;              // N tile 0..7
  const int kh = wave & 1;               // K half 0..1
  const int blk = blockIdx.x;
  const int g = blk >> 5;                // batch group 0..3
  const int ub_idx = blk & 31;           // unit-block within hidden dim
  const int gcol = ((nt >> 1) << 10) + ub_idx * UPB + ((nt & 1) << 4) + lr;

  short8 breg[16];
  {
    const short* wp = p.wt_hi + (size_t)gcol * HID + (kh << 9) + (lh << 3);
#pragma unroll
    for (int kk = 0; kk < 16; ++kk) breg[kk] = *(const short8*)(wp + (kk << 5));
  }

  const int b_loc = tid >> 5, u_loc = tid & 31;
  const int ci = ((g * GBS + b_loc) << 10) + ub_idx * UPB + u_loc;
  float creg = (tid < 512) ? p.cbuf[ci] : 0.f;

  const int asw = lr & 7;
  const unsigned long long fad =
      (unsigned long long)(p.flags + ((size_t)(g * BPG) + (lane & 31)) * 16);

  for (int t = p.t0; t < p.t1; ++t) {
    // ---- xw prefetch BEFORE the poll: latency rides under the flag wait
    float xv[4] = {0.f, 0.f, 0.f, 0.f};
    if (kh == 0) {
#pragma unroll
      for (int r = 0; r < 4; ++r) {
        const size_t rowi = (size_t)(t - p.t0) * BS + g * GBS + (lh << 2) + r;
        if (XW_F32) xv[r] = ((const float*)p.xw)[rowi * G4 + gcol];
        else        xv[r] = b2f(((const unsigned short*)p.xw)[rowi * G4 + gcol]);
      }
    }

    // ---- barrier-in: wait until the group has published h for step t
    if (t > 0 && wave == 0) {
      unsigned f0;
      do {
        asm volatile("global_load_dword %0, %1, off sc0 sc1\n\t"
                     "s_waitcnt vmcnt(0)"
                     : "=v"(f0) : "v"(fad) : "memory");
      } while (!__all(f0 >= (unsigned)t));
    }
    __syncthreads();

    const unsigned short* hb = p.hbuf + (size_t)(t & 1) * (BS * HID) + (size_t)g * GBS * HID;
    unsigned short* hw = p.hbuf + (size_t)((t + 1) & 1) * (BS * HID) + (size_t)g * GBS * HID;

    // ---- stage group h_t (32KB) -> LDS: 2 coherent gload_lds/wave
#pragma unroll
    for (int j = 0; j < 2; ++j) {
      const int i = (wave << 1) + j;
      const int row = i >> 1, half = i & 1;
      const int chunk = ((half << 6) + lane) ^ (row & 7);
      gload_lds16_cc(hb + row * HID + (chunk << 3), smem + (i << 10));
    }
    asm volatile("s_waitcnt vmcnt(0)" ::: "memory");
    __builtin_amdgcn_s_barrier();

    // ---- K loop: 16 x (ds_read_b128 + MFMA), B from registers
    floatx4 acc = {0.f, 0.f, 0.f, 0.f};
#pragma unroll
    for (int kk = 0; kk < 16; ++kk) {
      const int kc = (kh << 6) + (kk << 2) + lh;
      const short8 afr = *(const short8*)(smem + (lr << 11) + ((kc ^ asw) << 4));
      acc = __builtin_amdgcn_mfma_f32_16x16x32_bf16(afr, breg[kk], acc, 0, 0, 0);
    }

    // ---- gate partial sums to gsm (separate LDS region)
    {
      const int gate = nt >> 1, ub16 = (nt & 1) << 4;
#pragma unroll
      for (int r = 0; r < 4; ++r) {
        const int b = (lh << 2) + r;
        gsm[((kh << 2) + gate) * 528 + b * 33 + ub16 + lr] = acc[r] + xv[r];
      }
    }
    __syncthreads();

    // ---- elementwise update + DIRECT coherent publish (short store)
    if (tid < 512) {
      const int o = b_loc * 33 + u_loc;
      const float ig = gsm[o]            + gsm[4 * 528 + o];
      const float fg = gsm[1 * 528 + o]  + gsm[5 * 528 + o];
      const float gg = gsm[2 * 528 + o]  + gsm[6 * 528 + o];
      const float og = gsm[3 * 528 + o]  + gsm[7 * 528 + o];
      const float iv = 1.f / (1.f + __expf(-ig));
      const float fv = 1.f / (1.f + __expf(-fg));
      const float gv = tanhf(gg);
      const float ov = 1.f / (1.f + __expf(-og));
      const float cn = fv * creg + iv * gv;
      creg = cn;
      const float hv = ov * tanhf(cn);
      const unsigned hv16 = (unsigned)f2b(hv);
      const unsigned long long dst =
          (unsigned long long)(hw + (size_t)b_loc * HID + ub_idx * UPB + u_loc);
      asm volatile("global_store_short %0, %1, off sc0 sc1"
                   :: "v"(dst), "v"(hv16) : "memory");
      p.hs[((size_t)t * BS + g * GBS + b_loc) * HID + ub_idx * UPB + u_loc] = hv;
      if (p.wr_final && t == SEQ - 1) { p.h_final[ci] = hv; p.c_final[ci] = cn; }
    }
    asm volatile("s_waitcnt vmcnt(0)" ::: "memory");
    __syncthreads();
    if (tid == 0) {
      const unsigned long long fdst = (unsigned long long)(p.flags + (size_t)blk * 16);
      const unsigned fval = (unsigned)(t + 1);
      asm volatile("global_store_dword %0, %1, off sc0 sc1"
                   :: "v"(fdst), "v"(fval) : "memory");
    }
  }
  if (tid < 512) p.cbuf[ci] = creg;
}

// ---- gemm body: 128 blocks x 1024 threads (16 waves), 128x128 tiles
template<int XW_F32>
__device__ __forceinline__ void gemm_body(const FusedArgs& p, char* smem, int bi) {
  if (!p.genable) return;
  short* Al = (short*)smem;            // [128][40]
  short* Bl = (short*)(smem + 10240);  // [128][40]
  const int tid = threadIdx.x;
  const int wave = tid >> 6, lane = tid & 63;
  const int lr = lane & 15, lh = lane >> 4;
  const int wm = wave >> 2, wn = wave & 3;   // 4x4 wave grid, 32x32 each
  const int nmt = p.Mrows >> 7;
  const int tot = nmt << 5;                  // nmt x 32 tiles
  const int arow = tid >> 3, ak = (tid & 7) << 2;
  const int brow = tid >> 2, bk = (tid & 3) << 3;

  for (int tt = bi; tt < tot; tt += NBLK) {
    const int m0 = (tt >> 5) << 7, n0 = (tt & 31) << 7;
    const float* aptr = p.A + (size_t)(m0 + arow) * 1024 + ak;
    const short* bptr = p.BT + (size_t)(n0 + brow) * 1024 + bk;
    floatx4 acc[2][2] = {};
    for (int it = 0; it < 32; ++it) {
      __syncthreads();
      {
        const floatx4 fa = *(const floatx4*)(aptr + (it << 5));
        short4v s4;
#pragma unroll
        for (int e = 0; e < 4; ++e) s4[e] = (short)f2b(fa[e]);
        *(short4v*)&Al[arow * 40 + ak] = s4;
        if (tid < 512) {
          const short8 pb = *(const short8*)(bptr + (it << 5));
          *(short8*)&Bl[brow * 40 + bk] = pb;
        }
      }
      __syncthreads();
      short8 af[2], bf[2];
#pragma unroll
      for (int mt = 0; mt < 2; ++mt)
        af[mt] = *(const short8*)&Al[(wm * 32 + mt * 16 + lr) * 40 + lh * 8];
#pragma unroll
      for (int nt = 0; nt < 2; ++nt)
        bf[nt] = *(const short8*)&Bl[(wn * 32 + nt * 16 + lr) * 40 + lh * 8];
#pragma unroll
      for (int mt = 0; mt < 2; ++mt)
#pragma unroll
        for (int nt = 0; nt < 2; ++nt)
          acc[mt][nt] = __builtin_amdgcn_mfma_f32_16x16x32_bf16(af[mt], bf[nt], acc[mt][nt], 0, 0, 0);
    }
#pragma unroll
    for (int nt = 0; nt < 2; ++nt) {
      const int gc = n0 + wn * 32 + nt * 16 + lr;
      const float bv = p.bias[gc];
#pragma unroll
      for (int mt = 0; mt < 2; ++mt)
#pragma unroll
        for (int r = 0; r < 4; ++r) {
          const int gr = m0 + wm * 32 + mt * 16 + (lh << 2) + r;
          const float v = acc[mt][nt][r] + bv;
          if (XW_F32) ((float*)p.dst)[(size_t)gr * G4 + gc] = v;
          else        ((unsigned short*)p.dst)[(size_t)gr * G4 + gc] = f2b(v);
        }
    }
  }
}

// 256 blocks x 1024 threads, 1 block/CU: blocks 0..127 scan chunk c,
// blocks 128..255 compute xw for chunk c+1 (different CUs, full overlap).
template<int XW_F32>
__global__ __launch_bounds__(1024)
void lstm_fused(FusedArgs p) {
  __shared__ char smem[50688];
  if (blockIdx.x < NBLK) scan_body<XW_F32>(p, smem);
  else                   gemm_body<XW_F32>(p, smem, blockIdx.x - NBLK);
}

extern "C" void kernel_launch(void* const* d_in, const int* in_sizes, int n_in,
                              void* d_out, int out_size, void* d_ws, size_t ws_size,
                              hipStream_t stream) {
  const float* x    = (const float*)d_in[0];
  const float* Wii0 = (const float*)d_in[1];
  const float* Wii  = (const float*)d_in[2];
  const float* Whi  = (const float*)d_in[3];
  const float* bias = (const float*)d_in[4];
  float* out  = (float*)d_out;
  float* hs   = out;
  float* hfin = out + (size_t)SEQ * BS * HID;
  float* cfin = hfin + BS * HID;

  char* ws = (char*)d_ws;
  short* WT0 = (short*)ws;
  short* WT1 = WT0 + (size_t)G4 * 1024;
  short* WTh = WT1 + (size_t)G4 * 1024;
  unsigned short* hbuf = (unsigned short*)(WTh + (size_t)G4 * 1024);
  float* cbuf = (float*)(hbuf + 2 * BS * HID);
  unsigned int* flags = (unsigned int*)(cbuf + BS * HID);   // 128 * 64B
  char* tail = (char*)(flags + NBLK * 16);
  const size_t head = (size_t)(tail - ws);
  const size_t avail = (ws_size > head) ? ws_size - head : 0;
  const size_t perT_f32 = (size_t)BS * G4 * 4;   // 1 MiB per timestep
  const size_t perT_b16 = (size_t)BS * G4 * 2;

  // dual (ping-pong) xw buffers for producer/consumer overlap
  int chunk, xwF32;
  if      (avail >= 2 * 128 * perT_f32) { chunk = 128; xwF32 = 1; }
  else if (avail >= 2 * 64  * perT_f32) { chunk = 64;  xwF32 = 1; }
  else if (avail >= 2 * 32  * perT_f32) { chunk = 32;  xwF32 = 1; }
  else if (avail >= 2 * 32  * perT_b16) { chunk = 32;  xwF32 = 0; }
  else                                  { chunk = 8;   xwF32 = 0; }
  const size_t chunkBytes = (size_t)chunk * (xwF32 ? perT_f32 : perT_b16);
  void* xwbuf[2] = { (void*)tail, (void*)(tail + chunkBytes) };
  const int nc = SEQ / chunk;

  wtrans<<<dim3(128, 32), dim3(32, 8), 0, stream>>>(Wii0, WT0);
  wtrans<<<dim3(128, 32), dim3(32, 8), 0, stream>>>(Wii, WT1);
  wtrans<<<dim3(128, 32), dim3(32, 8), 0, stream>>>(Whi, WTh);

  const void* fused_fn = xwF32 ? reinterpret_cast<const void*>(&lstm_fused<1>)
                               : reinterpret_cast<const void*>(&lstm_fused<0>);

  for (int layer = 0; layer < 2; ++layer) {
    hipMemsetAsync(hbuf, 0, 2 * BS * HID * sizeof(unsigned short), stream);
    hipMemsetAsync(cbuf, 0, BS * HID * sizeof(float), stream);
    hipMemsetAsync(flags, 0, NBLK * 16 * sizeof(unsigned int), stream);

    if (layer == 0)   // prologue: only xw chunk not hidden behind a scan
      gemm_xw<<<dim3(32, chunk * BS / 128), dim3(256), 0, stream>>>(
          x, WT0, bias, xwbuf[0], xwF32);

    for (int c = 0; c < nc; ++c) {
      FusedArgs fa;
      fa.xw = xwbuf[c & 1];
      fa.wt_hi = WTh;
      fa.hbuf = hbuf;
      fa.cbuf = cbuf;
      fa.flags = flags;
      fa.hs = hs;
      fa.h_final = layer ? hfin : nullptr;
      fa.c_final = layer ? cfin : nullptr;
      fa.t0 = c * chunk;
      fa.t1 = (c + 1) * chunk;
      fa.wr_final = layer;
      // producer: xw for the next chunk (possibly the next layer's first)
      fa.bias = bias;
      fa.dst = xwbuf[(c + 1) & 1];
      fa.Mrows = chunk * BS;
      if (c < nc - 1) {
        fa.A = (layer ? hs : x) + (size_t)(c + 1) * chunk * BS * 1024;
        fa.BT = layer ? WT1 : WT0;
        fa.genable = 1;
      } else if (layer == 0) {
        fa.A = hs;                 // layer 1, chunk 0 (hs fully written)
        fa.BT = WT1;
        fa.genable = 1;
      } else {
        fa.A = x; fa.BT = WT1;
        fa.genable = 0;
      }
      void* args[] = { &fa };
      hipLaunchCooperativeKernel(fused_fn, dim3(2 * NBLK), dim3(1024), args, 0u, stream);
    }
  }
}

// Round 7
// 4816.875 us; speedup vs baseline: 12.7523x; 1.0281x over previous
//
#include <hip/hip_runtime.h>

typedef __attribute__((ext_vector_type(8))) short short8;
typedef __attribute__((ext_vector_type(4))) short short4v;
typedef __attribute__((ext_vector_type(4))) float floatx4;

#define SEQ 512
#define BS  64
#define HID 1024
#define G4  4096
#define NBLK 128
#define NGRP 4    // batch groups
#define BPG  32   // blocks per group
#define GBS  16   // batch rows per group
#define UPB  32   // hidden units per block

__device__ __forceinline__ unsigned short f2b(float f) {
  union { float f; unsigned u; } v; v.f = f;
  return (unsigned short)((v.u + 0x7FFFu + ((v.u >> 16) & 1u)) >> 16);
}
__device__ __forceinline__ float b2f(unsigned short s) {
  union { unsigned u; float f; } v; v.u = ((unsigned)s) << 16;
  return v.f;
}

// device-coherent (cross-XCD) async global->LDS: aux=17 = SC0|SC1
__device__ __forceinline__ void gload_lds16_cc(const void* g, void* l) {
  __builtin_amdgcn_global_load_lds(
      (const __attribute__((address_space(1))) unsigned int*)g,
      (__attribute__((address_space(3))) unsigned int*)l,
      16, 0, 17);
}

// ---- weight transpose+convert: W[1024][4096] f32 -> WT[4096][1024] bf16
__global__ void wtrans(const float* __restrict__ W, short* __restrict__ WT) {
  __shared__ float tile[32][33];
  const int tx = threadIdx.x, ty = threadIdx.y;
  const int n0 = blockIdx.x << 5, k0 = blockIdx.y << 5;
#pragma unroll
  for (int i = 0; i < 32; i += 8)
    tile[ty + i][tx] = W[(size_t)(k0 + ty + i) * G4 + n0 + tx];
  __syncthreads();
#pragma unroll
  for (int i = 0; i < 32; i += 8)
    WT[(size_t)(n0 + ty + i) * 1024 + k0 + tx] = (short)f2b(tile[tx][ty + i]);
}

// ---- standalone projection GEMM (prologue only): out[M][4096] = A @ WT^T + b
__global__ __launch_bounds__(256)
void gemm_xw(const float* __restrict__ A, const short* __restrict__ BT,
             const float* __restrict__ bias, void* __restrict__ xw, int xw_f32) {
  __shared__ short Al[128 * 40];
  __shared__ short Bl[128 * 40];
  const int tid = threadIdx.x;
  const int wave = tid >> 6, lane = tid & 63;
  const int lr = lane & 15, lh = lane >> 4;
  const int wm = wave >> 1, wn = wave & 1;
  const int m0 = blockIdx.y << 7;
  const int n0 = blockIdx.x << 7;
  const int arow = tid >> 1, akc = tid & 1;

  const float* aptr = A + (size_t)(m0 + arow) * 1024 + akc * 16;
  const short* bptr = BT + (size_t)(n0 + arow) * 1024 + akc * 16;

  floatx4 acc[4][4] = {};
  floatx4 fa[4];
  short8 pb0, pb1;
#pragma unroll
  for (int j = 0; j < 4; ++j) fa[j] = *(const floatx4*)(aptr + 4 * j);
  pb0 = *(const short8*)(bptr);
  pb1 = *(const short8*)(bptr + 8);

  for (int it = 0; it < 32; ++it) {
    __syncthreads();
    unsigned short us[16];
#pragma unroll
    for (int j = 0; j < 4; ++j)
#pragma unroll
      for (int e = 0; e < 4; ++e) us[4 * j + e] = f2b(fa[j][e]);
    short8 s0, s1;
#pragma unroll
    for (int e = 0; e < 8; ++e) { s0[e] = (short)us[e]; s1[e] = (short)us[8 + e]; }
    *(short8*)&Al[arow * 40 + akc * 16 + 0] = s0;
    *(short8*)&Al[arow * 40 + akc * 16 + 8] = s1;
    *(short8*)&Bl[arow * 40 + akc * 16 + 0] = pb0;
    *(short8*)&Bl[arow * 40 + akc * 16 + 8] = pb1;
    __syncthreads();
    if (it < 31) {
      const int k0 = (it + 1) << 5;
#pragma unroll
      for (int j = 0; j < 4; ++j) fa[j] = *(const floatx4*)(aptr + k0 + 4 * j);
      pb0 = *(const short8*)(bptr + k0);
      pb1 = *(const short8*)(bptr + k0 + 8);
    }
    short8 af[4], bf[4];
#pragma unroll
    for (int mt = 0; mt < 4; ++mt) af[mt] = *(const short8*)&Al[(wm * 64 + mt * 16 + lr) * 40 + lh * 8];
#pragma unroll
    for (int nt = 0; nt < 4; ++nt) bf[nt] = *(const short8*)&Bl[(wn * 64 + nt * 16 + lr) * 40 + lh * 8];
#pragma unroll
    for (int mt = 0; mt < 4; ++mt)
#pragma unroll
      for (int nt = 0; nt < 4; ++nt)
        acc[mt][nt] = __builtin_amdgcn_mfma_f32_16x16x32_bf16(af[mt], bf[nt], acc[mt][nt], 0, 0, 0);
  }
#pragma unroll
  for (int nt = 0; nt < 4; ++nt) {
    const int gcol = n0 + wn * 64 + nt * 16 + lr;
    const float bv = bias[gcol];
#pragma unroll
    for (int mt = 0; mt < 4; ++mt)
#pragma unroll
      for (int r = 0; r < 4; ++r) {
        const int grow = m0 + wm * 64 + mt * 16 + lh * 4 + r;
        const float v = acc[mt][nt][r] + bv;
        if (xw_f32) ((float*)xw)[(size_t)grow * G4 + gcol] = v;
        else        ((unsigned short*)xw)[(size_t)grow * G4 + gcol] = f2b(v);
      }
  }
}

struct FusedArgs {
  // scan (blocks 0..127): recurrence for chunk [t0,t1) reading xw
  const void* xw;
  const short* wt_hi;
  unsigned short* hbuf;    // [2][64*1024] bf16 ping-pong (coherent traffic)
  float* cbuf;             // [64*1024] f32 persistent cell state
  unsigned int* flags;     // [NBLK] u32 padded to 64B
  float* hs;               // [512][64][1024] f32 output
  float* h_final;
  float* c_final;
  int t0, t1, wr_final;
  // gemm (blocks 128..255): xw for the NEXT chunk -> dst
  const float* A;          // [Mrows][1024] f32
  const short* BT;         // WT [4096][1024] bf16
  const float* bias;
  void* dst;
  int Mrows, genable;
};

// ---- scan body: r5/r6 geometry; hs store moved off the publish critical path
template<int XW_F32>
__device__ __forceinline__ void scan_body(const FusedArgs& p, char* smem) {
  // [0,32768): h tile [16 rows][2048B] XOR-swizzled; [32768,+16896): gsm
  float* gsm = (float*)(smem + 32768);
  const int tid = threadIdx.x;
  const int wave = tid >> 6, lane = tid & 63;
  const int lr = lane & 15, lh = lane >> 4;
  const int nt = wave >> 1;              // N tile 0..7
  const int kh = wave & 1;               // K half 0..1
  const int blk = blockIdx.x;
  const int g = blk >> 5;                // batch group 0..3
  const int ub_idx = blk & 31;           // unit-block within hidden dim
  const int gcol = ((nt >> 1) << 10) + ub_idx * UPB + ((nt & 1) << 4) + lr;

  short8 breg[16];
  {
    const short* wp = p.wt_hi + (size_t)gcol * HID + (kh << 9) + (lh << 3);
#pragma unroll
    for (int kk = 0; kk < 16; ++kk) breg[kk] = *(const short8*)(wp + (kk << 5));
  }

  const int b_loc = tid >> 5, u_loc = tid & 31;
  const int ci = ((g * GBS + b_loc) << 10) + ub_idx * UPB + u_loc;
  float creg = (tid < 512) ? p.cbuf[ci] : 0.f;

  const int asw = lr & 7;
  const unsigned long long fad =
      (unsigned long long)(p.flags + ((size_t)(g * BPG) + (lane & 31)) * 16);

  for (int t = p.t0; t < p.t1; ++t) {
    // ---- xw prefetch BEFORE the poll: latency rides under the flag wait
    float xv[4] = {0.f, 0.f, 0.f, 0.f};
    if (kh == 0) {
#pragma unroll
      for (int r = 0; r < 4; ++r) {
        const size_t rowi = (size_t)(t - p.t0) * BS + g * GBS + (lh << 2) + r;
        if (XW_F32) xv[r] = ((const float*)p.xw)[rowi * G4 + gcol];
        else        xv[r] = b2f(((const unsigned short*)p.xw)[rowi * G4 + gcol]);
      }
    }

    // ---- barrier-in: wait until the group has published h for step t
    if (t > 0 && wave == 0) {
      unsigned f0;
      do {
        asm volatile("global_load_dword %0, %1, off sc0 sc1\n\t"
                     "s_waitcnt vmcnt(0)"
                     : "=v"(f0) : "v"(fad) : "memory");
      } while (!__all(f0 >= (unsigned)t));
    }
    __syncthreads();

    const unsigned short* hb = p.hbuf + (size_t)(t & 1) * (BS * HID) + (size_t)g * GBS * HID;
    unsigned short* hw = p.hbuf + (size_t)((t + 1) & 1) * (BS * HID) + (size_t)g * GBS * HID;

    // ---- stage group h_t (32KB) -> LDS: 2 coherent gload_lds/wave
#pragma unroll
    for (int j = 0; j < 2; ++j) {
      const int i = (wave << 1) + j;
      const int row = i >> 1, half = i & 1;
      const int chunk = ((half << 6) + lane) ^ (row & 7);
      gload_lds16_cc(hb + row * HID + (chunk << 3), smem + (i << 10));
    }
    asm volatile("s_waitcnt vmcnt(0)" ::: "memory");
    __builtin_amdgcn_s_barrier();

    // ---- K loop: 16 x (ds_read_b128 + MFMA), B from registers
    floatx4 acc = {0.f, 0.f, 0.f, 0.f};
#pragma unroll
    for (int kk = 0; kk < 16; ++kk) {
      const int kc = (kh << 6) + (kk << 2) + lh;
      const short8 afr = *(const short8*)(smem + (lr << 11) + ((kc ^ asw) << 4));
      acc = __builtin_amdgcn_mfma_f32_16x16x32_bf16(afr, breg[kk], acc, 0, 0, 0);
    }

    // ---- gate partial sums to gsm (separate LDS region)
    {
      const int gate = nt >> 1, ub16 = (nt & 1) << 4;
#pragma unroll
      for (int r = 0; r < 4; ++r) {
        const int b = (lh << 2) + r;
        gsm[((kh << 2) + gate) * 528 + b * 33 + ub16 + lr] = acc[r] + xv[r];
      }
    }
    __syncthreads();

    // ---- elementwise update + coherent publish; hs store deferred
    float hv = 0.f, cn = 0.f;
    if (tid < 512) {
      const int o = b_loc * 33 + u_loc;
      const float ig = gsm[o]            + gsm[4 * 528 + o];
      const float fg = gsm[1 * 528 + o]  + gsm[5 * 528 + o];
      const float gg = gsm[2 * 528 + o]  + gsm[6 * 528 + o];
      const float og = gsm[3 * 528 + o]  + gsm[7 * 528 + o];
      const float iv = 1.f / (1.f + __expf(-ig));
      const float fv = 1.f / (1.f + __expf(-fg));
      const float gv = tanhf(gg);
      const float ov = 1.f / (1.f + __expf(-og));
      cn = fv * creg + iv * gv;
      creg = cn;
      hv = ov * tanhf(cn);
      const unsigned hv16 = (unsigned)f2b(hv);
      const unsigned long long dst =
          (unsigned long long)(hw + (size_t)b_loc * HID + ub_idx * UPB + u_loc);
      asm volatile("global_store_short %0, %1, off sc0 sc1"
                   :: "v"(dst), "v"(hv16) : "memory");
    }
    asm volatile("s_waitcnt vmcnt(0)" ::: "memory");  // only the 2B publish
    __syncthreads();
    if (tid == 0) {
      const unsigned long long fdst = (unsigned long long)(p.flags + (size_t)blk * 16);
      const unsigned fval = (unsigned)(t + 1);
      asm volatile("global_store_dword %0, %1, off sc0 sc1"
                   :: "v"(fdst), "v"(fval) : "memory");
    }
    // hs write off the critical path (next step's waits will absorb it)
    if (tid < 512) {
      p.hs[((size_t)t * BS + g * GBS + b_loc) * HID + ub_idx * UPB + u_loc] = hv;
      if (p.wr_final && t == SEQ - 1) { p.h_final[ci] = hv; p.c_final[ci] = cn; }
    }
  }
  if (tid < 512) p.cbuf[ci] = creg;
}

// ---- gemm body: 128 blocks x 1024 threads (16 waves), 128x128 tile,
// software-pipelined like gemm_xw (prefetch next K-slab before LDS write).
template<int XW_F32>
__device__ __forceinline__ void gemm_body(const FusedArgs& p, char* smem, int bi) {
  if (!p.genable) return;
  short* Al = (short*)smem;            // [128][40]
  short* Bl = (short*)(smem + 10240);  // [128][40]
  const int tid = threadIdx.x;
  const int wave = tid >> 6, lane = tid & 63;
  const int lr = lane & 15, lh = lane >> 4;
  const int wm = wave >> 2, wn = wave & 3;   // 4x4 wave grid, 32x32 each
  const int nmt = p.Mrows >> 7;
  const int tot = nmt << 5;                  // nmt x 32 tiles of 128x128
  const int srow = tid >> 3, scol = (tid & 7) << 2;   // 4 elems/thread

  for (int tt = bi; tt < tot; tt += NBLK) {
    const int m0 = (tt >> 5) << 7, n0 = (tt & 31) << 7;
    const float* aptr = p.A + (size_t)(m0 + srow) * 1024 + scol;
    const short* bptr = p.BT + (size_t)(n0 + srow) * 1024 + scol;
    floatx4 acc[2][2] = {};
    floatx4 fa = *(const floatx4*)aptr;
    short4v pb = *(const short4v*)bptr;
    for (int it = 0; it < 32; ++it) {
      __syncthreads();
      {
        short4v s4;
#pragma unroll
        for (int e = 0; e < 4; ++e) s4[e] = (short)f2b(fa[e]);
        *(short4v*)&Al[srow * 40 + scol] = s4;
        *(short4v*)&Bl[srow * 40 + scol] = pb;
      }
      __syncthreads();
      if (it < 31) {
        fa = *(const floatx4*)(aptr + ((it + 1) << 5));
        pb = *(const short4v*)(bptr + ((it + 1) << 5));
      }
      short8 af[2], bf[2];
#pragma unroll
      for (int mt = 0; mt < 2; ++mt)
        af[mt] = *(const short8*)&Al[(wm * 32 + mt * 16 + lr) * 40 + lh * 8];
#pragma unroll
      for (int nt = 0; nt < 2; ++nt)
        bf[nt] = *(const short8*)&Bl[(wn * 32 + nt * 16 + lr) * 40 + lh * 8];
#pragma unroll
      for (int mt = 0; mt < 2; ++mt)
#pragma unroll
        for (int nt = 0; nt < 2; ++nt)
          acc[mt][nt] = __builtin_amdgcn_mfma_f32_16x16x32_bf16(af[mt], bf[nt], acc[mt][nt], 0, 0, 0);
    }
#pragma unroll
    for (int nt = 0; nt < 2; ++nt) {
      const int gc = n0 + wn * 32 + nt * 16 + lr;
      const float bv = p.bias[gc];
#pragma unroll
      for (int mt = 0; mt < 2; ++mt)
#pragma unroll
        for (int r = 0; r < 4; ++r) {
          const int gr = m0 + wm * 32 + mt * 16 + (lh << 2) + r;
          const float v = acc[mt][nt][r] + bv;
          if (XW_F32) ((float*)p.dst)[(size_t)gr * G4 + gc] = v;
          else        ((unsigned short*)p.dst)[(size_t)gr * G4 + gc] = f2b(v);
        }
    }
  }
}

// 256 blocks x 1024 threads. LDS bumped to 82.5KB to FORCE 1 block/CU:
// scan blocks (0..127) and gemm blocks (128..255) land on different CUs.
template<int XW_F32>
__global__ __launch_bounds__(1024)
void lstm_fused(FusedArgs p) {
  __shared__ __align__(16) char smem[84480];
  if (blockIdx.x < NBLK) scan_body<XW_F32>(p, smem);
  else                   gemm_body<XW_F32>(p, smem, blockIdx.x - NBLK);
}

extern "C" void kernel_launch(void* const* d_in, const int* in_sizes, int n_in,
                              void* d_out, int out_size, void* d_ws, size_t ws_size,
                              hipStream_t stream) {
  const float* x    = (const float*)d_in[0];
  const float* Wii0 = (const float*)d_in[1];
  const float* Wii  = (const float*)d_in[2];
  const float* Whi  = (const float*)d_in[3];
  const float* bias = (const float*)d_in[4];
  float* out  = (float*)d_out;
  float* hs   = out;
  float* hfin = out + (size_t)SEQ * BS * HID;
  float* cfin = hfin + BS * HID;

  char* ws = (char*)d_ws;
  short* WT0 = (short*)ws;
  short* WT1 = WT0 + (size_t)G4 * 1024;
  short* WTh = WT1 + (size_t)G4 * 1024;
  unsigned short* hbuf = (unsigned short*)(WTh + (size_t)G4 * 1024);
  float* cbuf = (float*)(hbuf + 2 * BS * HID);
  unsigned int* flags = (unsigned int*)(cbuf + BS * HID);   // 128 * 64B
  char* tail = (char*)(flags + NBLK * 16);
  const size_t head = (size_t)(tail - ws);
  const size_t avail = (ws_size > head) ? ws_size - head : 0;
  const size_t perT_f32 = (size_t)BS * G4 * 4;   // 1 MiB per timestep
  const size_t perT_b16 = (size_t)BS * G4 * 2;

  // dual (ping-pong) xw buffers for producer/consumer overlap
  int chunk, xwF32;
  if      (avail >= 2 * 128 * perT_f32) { chunk = 128; xwF32 = 1; }
  else if (avail >= 2 * 64  * perT_f32) { chunk = 64;  xwF32 = 1; }
  else if (avail >= 2 * 32  * perT_f32) { chunk = 32;  xwF32 = 1; }
  else if (avail >= 2 * 32  * perT_b16) { chunk = 32;  xwF32 = 0; }
  else                                  { chunk = 8;   xwF32 = 0; }
  const size_t chunkBytes = (size_t)chunk * (xwF32 ? perT_f32 : perT_b16);
  void* xwbuf[2] = { (void*)tail, (void*)(tail + chunkBytes) };
  const int nc = SEQ / chunk;

  wtrans<<<dim3(128, 32), dim3(32, 8), 0, stream>>>(Wii0, WT0);
  wtrans<<<dim3(128, 32), dim3(32, 8), 0, stream>>>(Wii, WT1);
  wtrans<<<dim3(128, 32), dim3(32, 8), 0, stream>>>(Whi, WTh);

  const void* fused_fn = xwF32 ? reinterpret_cast<const void*>(&lstm_fused<1>)
                               : reinterpret_cast<const void*>(&lstm_fused<0>);

  for (int layer = 0; layer < 2; ++layer) {
    hipMemsetAsync(hbuf, 0, 2 * BS * HID * sizeof(unsigned short), stream);
    hipMemsetAsync(cbuf, 0, BS * HID * sizeof(float), stream);
    hipMemsetAsync(flags, 0, NBLK * 16 * sizeof(unsigned int), stream);

    if (layer == 0)   // prologue: only xw chunk not hidden behind a scan
      gemm_xw<<<dim3(32, chunk * BS / 128), dim3(256), 0, stream>>>(
          x, WT0, bias, xwbuf[0], xwF32);

    for (int c = 0; c < nc; ++c) {
      FusedArgs fa;
      fa.xw = xwbuf[c & 1];
      fa.wt_hi = WTh;
      fa.hbuf = hbuf;
      fa.cbuf = cbuf;
      fa.flags = flags;
      fa.hs = hs;
      fa.h_final = layer ? hfin : nullptr;
      fa.c_final = layer ? cfin : nullptr;
      fa.t0 = c * chunk;
      fa.t1 = (c + 1) * chunk;
      fa.wr_final = layer;
      // producer: xw for the next chunk (possibly the next layer's first)
      fa.bias = bias;
      fa.dst = xwbuf[(c + 1) & 1];
      fa.Mrows = chunk * BS;
      if (c < nc - 1) {
        fa.A = (layer ? hs : x) + (size_t)(c + 1) * chunk * BS * 1024;
        fa.BT = layer ? WT1 : WT0;
        fa.genable = 1;
      } else if (layer == 0) {
        fa.A = hs;                 // layer 1, chunk 0 (hs fully written)
        fa.BT = WT1;
        fa.genable = 1;
      } else {
        fa.A = x; fa.BT = WT1;
        fa.genable = 0;
      }
      void* args[] = { &fa };
      hipLaunchCooperativeKernel(fused_fn, dim3(2 * NBLK), dim3(1024), args, 0u, stream);
    }
  }
}